// Round 7
// baseline (209.661 us; speedup 1.0000x reference)
//
#include <hip/hip_runtime.h>
#include <math.h>

// YOLO loss — max-occupancy sweep version.
// One wave per 64-cell tile. pred consumed as a coalesced float2 stream in
// "sweep order" (j = lane + 64*i, i=0..14): cls-part float2s (j%15>=5) are
// differenced against tcls in-register; box-part float2s (j%15<5) are parked
// in a tiny packed LDS record (11 words/cell, stride-11 -> conflict-free).
// Per-cell box math then reads its 10 floats from LDS (intra-wave RAW only,
// no barrier). LDS = 11.3 KB/block; __launch_bounds__(256,8) pins VGPR<=64
// -> 32 waves/CU theoretical (vs ~12-16 in all prior rounds). Tests the
// wave-starvation hypothesis for the 62-us plateau.

#define BLOCK 256
#define WPB 4            // waves per block
#define CPW 64           // cells per wave-tile
#define CW  11           // padded LDS words per cell record (10 + 1 pad)

typedef float vf4 __attribute__((ext_vector_type(4)));

__global__ __launch_bounds__(BLOCK, 8) void k_yolo(
    const float2* __restrict__ pred2,    // pred as float2 (15 per cell)
    const vf4*    __restrict__ tbox4,    // (cell) float4
    const float2* __restrict__ tcls2,    // tcls as float2 (10 per cell)
    const int*    __restrict__ mask,
    float4*       __restrict__ partial,
    int n_cells)
{
    __shared__ float  sbox[WPB][CPW * CW];   // 4 * 2816 B = 11264 B
    __shared__ float4 swr[WPB];
    const int tid  = threadIdx.x;
    const int lane = tid & 63;
    const int w    = tid >> 6;
    const long long nc     = n_cells;
    const long long ntiles = (nc + CPW - 1) / CPW;
    const long long g      = (long long)blockIdx.x * WPB + w;
    const long long cell0  = g * CPW;                  // unclamped (validity)
    long long gt   = (g < ntiles) ? g : (ntiles - 1);
    long long base = gt * CPW;
    if (base + CPW > nc) base = nc - CPW;
    if (base < 0) base = 0;

    float* sb = &sbox[w][0];

    // ---- per-cell direct loads (coalesced) ----
    int mraw = mask[base + lane];
    vf4 tb   = tbox4[base + lane];
    const bool vf    = (cell0 + (long long)lane) < nc;
    const int  mflag = vf ? mraw : 0;
    const float mff  = (float)mflag;
    const float vff  = vf ? 1.0f : 0.0f;
    const unsigned long long mbits = __ballot(mflag != 0);

    float cls = 0.f;
    const float2* pbase = pred2 + base * 15;
    const float2* cbase = tcls2 + base * 10;

    // ---- sweep pred in two halves (caps live VGPRs) ----
    #pragma unroll
    for (int h = 0; h < 2; ++h) {
        const int i0 = (h == 0) ? 0 : 8;
        const int in = (h == 0) ? 8 : 7;
        float2 p2[8], t2[8];
        #pragma unroll
        for (int i = 0; i < 8; ++i) {
            if (i >= in) break;
            int j = lane + 64 * (i0 + i);
            int c = j / 15, r = j - 15 * c;
            p2[i] = pbase[j];
            int off = (r >= 5) ? (r - 5) : 0;     // clamp box-lanes onto a needed line
            t2[i] = cbase[c * 10 + off];
        }
        #pragma unroll
        for (int i = 0; i < 8; ++i) {
            if (i >= in) break;
            int j = lane + 64 * (i0 + i);
            int c = j / 15, r = j - 15 * c;
            if (r < 5) {                          // box float2 -> packed LDS record
                sb[c * CW + r * 2]     = p2[i].x;
                sb[c * CW + r * 2 + 1] = p2[i].y;
            } else {                              // cls float2 -> accumulate
                float keep = ((((mbits >> c) & 1ull) != 0ull) &&
                              (cell0 + (long long)c < nc)) ? 1.0f : 0.0f;
                float d0 = t2[i].x - p2[i].x, d1 = t2[i].y - p2[i].y;
                cls += keep * (d0 * d0 + d1 * d1);
            }
        }
    }

    // ---- intra-wave LDS RAW: drain DS pipe, then per-cell box math ----
    __builtin_amdgcn_s_waitcnt(0xC07F);           // lgkmcnt(0)
    __asm__ volatile("" ::: "memory");

    float p[10];
    #pragma unroll
    for (int k = 0; k < 10; ++k) p[k] = sb[lane * CW + k];

    float noobj, reg, cont;
    {
        float txc = tb.x / 14.0f, tyc = tb.y / 14.0f;
        float t0 = txc - 0.5f * tb.z, t1 = tyc - 0.5f * tb.w;
        float t2_ = txc + 0.5f * tb.z, t3 = tyc + 0.5f * tb.w;
        float area_t = (t2_ - t0) * (t3 - t1);
        // box0 = p[0..4] (x,y,w,h,conf); box1 = p[5..9]
        float bx[2] = { p[0], p[5] }, by[2] = { p[1], p[6] };
        float bw[2] = { p[2], p[7] }, bh[2] = { p[3], p[8] };
        float bcf[2] = { p[4], p[9] };
        float iou[2];
        #pragma unroll
        for (int b = 0; b < 2; ++b) {
            float px = bx[b] / 14.0f, py = by[b] / 14.0f;
            float q0 = px - 0.5f * bw[b], q1 = py - 0.5f * bh[b];
            float q2 = px + 0.5f * bw[b], q3 = py + 0.5f * bh[b];
            float lt0 = fmaxf(t0, q0), lt1 = fmaxf(t1, q1);
            float rb0 = fminf(t2_, q2), rb1 = fminf(t3, q3);
            float ww = fmaxf(rb0 - lt0, 0.f), hh = fmaxf(rb1 - lt1, 0.f);
            float inter = ww * hh;
            float area_p = (q2 - q0) * (q3 - q1);
            iou[b] = inter / (area_t + area_p - inter);
        }
        int bi = (iou[1] > iou[0]) ? 1 : 0;       // jnp.argmax first-max rule
        float dx = bx[bi] - tb.x, dy = by[bi] - tb.y;
        float swd = sqrtf(bw[bi]) - sqrtf(tb.z);  // inputs > 0
        float shd = sqrtf(bh[bi]) - sqrtf(tb.w);
        reg  = mff * 5.0f * (dx*dx + dy*dy + swd*swd + shd*shd);
        float dco = iou[bi] - bcf[bi];
        cont = mff * dco * dco;
        noobj = (vff - mff) * 0.5f * (p[4] * p[4] + p[9] * p[9]);
    }

    // ---- wave shuffle reduce, block reduce, store partial ----
    #pragma unroll
    for (int off = 32; off; off >>= 1) {
        cls   += __shfl_down(cls,   off, 64);
        noobj += __shfl_down(noobj, off, 64);
        reg   += __shfl_down(reg,   off, 64);
        cont  += __shfl_down(cont,  off, 64);
    }
    if (lane == 0) swr[w] = make_float4(cls, noobj, reg, cont);
    __syncthreads();
    if (tid == 0) {
        float4 a = swr[0];
        #pragma unroll
        for (int i = 1; i < WPB; ++i) {
            float4 b = swr[i];
            a.x += b.x; a.y += b.y; a.z += b.z; a.w += b.w;
        }
        partial[blockIdx.x] = a;
    }
}

__global__ __launch_bounds__(256) void k_final(
    const float4* __restrict__ partial, int nblocks,
    float* __restrict__ out, float invN)
{
    float4 acc = make_float4(0.f, 0.f, 0.f, 0.f);
    for (int b = threadIdx.x; b < nblocks; b += 256) {
        float4 p = partial[b];
        acc.x += p.x; acc.y += p.y; acc.z += p.z; acc.w += p.w;
    }
    #pragma unroll
    for (int off = 32; off; off >>= 1) {
        acc.x += __shfl_down(acc.x, off, 64);
        acc.y += __shfl_down(acc.y, off, 64);
        acc.z += __shfl_down(acc.z, off, 64);
        acc.w += __shfl_down(acc.w, off, 64);
    }
    __shared__ float4 sw[4];
    int lane = threadIdx.x & 63, w = threadIdx.x >> 6;
    if (lane == 0) sw[w] = acc;
    __syncthreads();
    if (threadIdx.x == 0) {
        float cls = 0.f, noobj = 0.f, reg = 0.f, cont = 0.f;
        #pragma unroll
        for (int i = 0; i < 4; ++i) {
            cls += sw[i].x; noobj += sw[i].y; reg += sw[i].z; cont += sw[i].w;
        }
        out[0] = (cls + noobj + reg + cont) * invN;
        out[1] = reg;
        out[2] = cont;
        out[3] = noobj;
        out[4] = cls;
    }
}

extern "C" void kernel_launch(void* const* d_in, const int* in_sizes, int n_in,
                              void* d_out, int out_size, void* d_ws, size_t ws_size,
                              hipStream_t stream) {
    const float2* pred2 = (const float2*)d_in[0];  // (N,14,14,30) f32
    const vf4*    tbox4 = (const vf4*)d_in[1];     // (N,14,14,4)  f32
    const float2* tcls2 = (const float2*)d_in[2];  // (N,14,14,20) f32
    const int*    mask  = (const int*)d_in[3];     // (N,14,14)    int32 (verified R1)
    float* out = (float*)d_out;
    float4* partial = (float4*)d_ws;

    int n_cells = in_sizes[3];
    int N = in_sizes[0] / (14 * 14 * 30);
    long long ntiles = (n_cells + CPW - 1) / CPW;           // 12544
    int nblocks = (int)((ntiles + WPB - 1) / WPB);          // 3136

    hipLaunchKernelGGL(k_yolo, dim3(nblocks), dim3(BLOCK), 0, stream,
                       pred2, tbox4, tcls2, mask, partial, n_cells);
    hipLaunchKernelGGL(k_final, dim3(1), dim3(256), 0, stream,
                       partial, nblocks, out, 1.0f / (float)N);
}